// Round 5
// baseline (172.659 us; speedup 1.0000x reference)
//
#include <hip/hip_runtime.h>

// PillarVFE fused. k1: feature moments (65) + per-voxel packed record
// (-mx,-my,-mz,-cx,-cy,-cz bf16, cnt), register-double-buffered, exact grid.
// k2: reduce 2500 partial rows -> per-channel a,b.
// k3: A = [xyzw, -mean, -center]*mask in K-slots, B = a*W'' (bf16), C = 0,
// D = a*x exactly; out = relu(b + max_rows D). Prefetched, exact grid.

typedef __attribute__((ext_vector_type(8))) short short8;     // 8 bf16
typedef __attribute__((ext_vector_type(16))) float floatx16;  // 32x32 MFMA C/D

namespace {
constexpr int V_    = 100000;
constexpr int P_    = 32;
constexpr int COUT  = 64;
constexpr int NF    = 10;
constexpr int NMOM  = 65;
constexpr int PSTRIDE = 72;
constexpr int K1_BLOCKS = 2500;   // 8 voxels/iter x 5 iters = 100000 exactly
constexpr int K1_ITERS  = 5;
constexpr int K3_BLOCKS = 3125;   // 12500 waves x 8 iters = 100000 exactly
constexpr int K3_WAVES  = 12500;
constexpr int K3_ITERS  = 8;
constexpr int K2_CHUNKS = 10;     // 10 x 250 rows

constexpr float VX_ = 0.16f, VY_ = 0.16f, VZ_ = 4.0f;
constexpr float XOFF_ = 0.08f, YOFF_ = -39.60f, ZOFF_ = -1.0f;
constexpr float EPS_ = 0.001f;
}

__device__ __forceinline__ unsigned f2bfu(float x) {  // RNE -> 16-bit value
  unsigned u = __builtin_bit_cast(unsigned, x);
  u += 0x7fffu + ((u >> 16) & 1u);
  return u >> 16;
}

// Pass 1: 65 feature moments (per-lane acc -> wave butterfly -> block reduce)
// + per-voxel record {pack(-mx,-my), pack(-mz,-cx), pack(-cy,-cz), cnt}.
__global__ __launch_bounds__(256) void k1_stats(
    const float* __restrict__ vf, const int* __restrict__ npts,
    const int* __restrict__ coords, float* __restrict__ partials,
    int4* __restrict__ meanws)
{
  float acc[NMOM];
  #pragma unroll
  for (int i = 0; i < NMOM; ++i) acc[i] = 0.f;

  const int tid = threadIdx.x;
  const int sub = tid >> 5;
  const int p   = tid & 31;
  const int v0  = blockIdx.x * 8 + sub;

  // prefetch iteration 0
  float4 pt_n = ((const float4*)vf)[v0 * P_ + p];
  int    cnt_n = npts[v0];
  int4   cd_n  = ((const int4*)coords)[v0];

  #pragma unroll
  for (int it = 0; it < K1_ITERS; ++it) {
    const float4 pt = pt_n;
    const int    cnt = cnt_n;
    const int4   cd  = cd_n;
    const int v = v0 + it * (K1_BLOCKS * 8);
    if (it + 1 < K1_ITERS) {
      const int vn = v0 + (it + 1) * (K1_BLOCKS * 8);
      pt_n  = ((const float4*)vf)[vn * P_ + p];
      cnt_n = npts[vn];
      cd_n  = ((const int4*)coords)[vn];
    }

    float sx = pt.x, sy = pt.y, sz = pt.z;
    #pragma unroll
    for (int m = 16; m >= 1; m >>= 1) {
      sx += __shfl_xor(sx, m, 32);
      sy += __shfl_xor(sy, m, 32);
      sz += __shfl_xor(sz, m, 32);
    }
    const float cf = (float)cnt;
    const float mx = sx / cf, my = sy / cf, mz = sz / cf;
    const float cx = (float)cd.w * VX_ + XOFF_;
    const float cy = (float)cd.z * VY_ + YOFF_;
    const float cz = (float)cd.y * VZ_ + ZOFF_;

    if (p == 0) {
      unsigned nm01 = f2bfu(-mx) | (f2bfu(-my) << 16);
      unsigned nm23 = f2bfu(-mz) | (f2bfu(-cx) << 16);
      unsigned nm45 = f2bfu(-cy) | (f2bfu(-cz) << 16);
      meanws[v] = make_int4((int)nm01, (int)nm23, (int)nm45, cnt);
    }

    const float msk = (p < cnt) ? 1.0f : 0.0f;
    float f[NF];
    f[0] = pt.x * msk; f[1] = pt.y * msk; f[2] = pt.z * msk; f[3] = pt.w * msk;
    f[4] = (pt.x - mx) * msk; f[5] = (pt.y - my) * msk; f[6] = (pt.z - mz) * msk;
    f[7] = (pt.x - cx) * msk; f[8] = (pt.y - cy) * msk; f[9] = (pt.z - cz) * msk;

    #pragma unroll
    for (int c = 0; c < NF; ++c) acc[c] += f[c];
    int idx = NF;
    #pragma unroll
    for (int c = 0; c < NF; ++c)
      #pragma unroll
      for (int c2 = c; c2 < NF; ++c2)
        acc[idx++] += f[c] * f[c2];
  }

  #pragma unroll
  for (int i = 0; i < NMOM; ++i) {
    float a = acc[i];
    #pragma unroll
    for (int m = 32; m >= 1; m >>= 1) a += __shfl_xor(a, m, 64);
    acc[i] = a;
  }

  __shared__ float red[4][NMOM];
  if ((tid & 63) == 0) {
    int w = tid >> 6;
    #pragma unroll
    for (int i = 0; i < NMOM; ++i) red[w][i] = acc[i];
  }
  __syncthreads();
  if (tid < NMOM) {
    partials[blockIdx.x * PSTRIDE + tid] =
        (red[0][tid] + red[1][tid]) + (red[2][tid] + red[3][tid]);
  }
}

// Pass 2: reduce 2500 rows -> a,b per channel.
__global__ __launch_bounds__(704) void k2_finalize(
    const float* __restrict__ partials, const float* __restrict__ Wm,
    const float* __restrict__ gamma, const float* __restrict__ beta,
    float* __restrict__ ab)
{
  __shared__ float s1[K2_CHUNKS * NMOM];
  __shared__ double S[NMOM];
  const int t = threadIdx.x;

  if (t < K2_CHUNKS * NMOM) {   // 650 threads
    const int col = t % NMOM, chunk = t / NMOM;
    const int base = chunk * 250;
    float a0 = 0.f, a1 = 0.f, a2 = 0.f, a3 = 0.f, a4 = 0.f;
    #pragma unroll 5
    for (int i = 0; i < 250; i += 5) {
      a0 += partials[(base + i + 0) * PSTRIDE + col];
      a1 += partials[(base + i + 1) * PSTRIDE + col];
      a2 += partials[(base + i + 2) * PSTRIDE + col];
      a3 += partials[(base + i + 3) * PSTRIDE + col];
      a4 += partials[(base + i + 4) * PSTRIDE + col];
    }
    s1[chunk * NMOM + col] = ((a0 + a1) + (a2 + a3)) + a4;
  }
  __syncthreads();
  if (t < NMOM) {
    double d = 0.0;
    #pragma unroll
    for (int c = 0; c < K2_CHUNKS; ++c) d += (double)s1[c * NMOM + t];
    S[t] = d;
  }
  __syncthreads();
  if (t < COUT) {
    const double N = (double)V_ * (double)P_;
    double w[NF];
    #pragma unroll
    for (int c = 0; c < NF; ++c) w[c] = (double)Wm[t * NF + c];
    double mean = 0.0;
    #pragma unroll
    for (int c = 0; c < NF; ++c) mean += w[c] * S[c];
    mean /= N;
    double ex2 = 0.0;
    int idx = NF;
    #pragma unroll
    for (int c = 0; c < NF; ++c)
      #pragma unroll
      for (int c2 = c; c2 < NF; ++c2) {
        double coef = (c == c2) ? 1.0 : 2.0;
        ex2 += coef * w[c] * w[c2] * S[idx++];
      }
    ex2 /= N;
    double var = ex2 - mean * mean;
    double rs = 1.0 / sqrt(var + (double)EPS_);
    double a = (double)gamma[t] * rs;
    double b = (double)beta[t] - mean * a;
    ab[t] = (float)a;
    ab[COUT + t] = (float)b;
  }
}

// Pass 3: one wave = one voxel/iter, prefetched. A K-slots = [xyzw,-m,-ctr]*mask,
// C = 0 -> D = a*x exactly; out = relu(b + max over 32 rows).
__global__ __launch_bounds__(256) void k3_mfma(
    const float* __restrict__ vf, const float* __restrict__ Wm,
    const float* __restrict__ ab, const int4* __restrict__ meanws,
    float* __restrict__ out)
{
  const int tid  = threadIdx.x;
  const int lane = tid & 63;
  const int p    = lane & 31;
  const int half = lane >> 5;
  const int waveG = blockIdx.x * 4 + (tid >> 6);   // 0..12499

  // B fragments: B[k][n], n = lane&31, k = half*8+j.
  // k0..3: a*(W0+W4+W7, W1+W5+W8, W2+W6+W9, W3); k4..9: a*(W4..W9).
  const float a0 = ab[p],      b0 = ab[COUT + p];
  const float a1 = ab[32 + p], b1 = ab[COUT + 32 + p];
  short8 bf0, bf1;
  {
    const float* w0 = &Wm[p * NF];
    const float* w1 = &Wm[(32 + p) * NF];
    float t0[NF], t1[NF];
    t0[0] = a0 * (w0[0] + w0[4] + w0[7]);
    t0[1] = a0 * (w0[1] + w0[5] + w0[8]);
    t0[2] = a0 * (w0[2] + w0[6] + w0[9]);
    t0[3] = a0 * w0[3];
    t1[0] = a1 * (w1[0] + w1[4] + w1[7]);
    t1[1] = a1 * (w1[1] + w1[5] + w1[8]);
    t1[2] = a1 * (w1[2] + w1[6] + w1[9]);
    t1[3] = a1 * w1[3];
    #pragma unroll
    for (int k = 4; k < NF; ++k) { t0[k] = a0 * w0[k]; t1[k] = a1 * w1[k]; }

    uint4 bd0, bd1;
    unsigned p001 = f2bfu(t0[0]) | (f2bfu(t0[1]) << 16);
    unsigned p023 = f2bfu(t0[2]) | (f2bfu(t0[3]) << 16);
    unsigned p045 = f2bfu(t0[4]) | (f2bfu(t0[5]) << 16);
    unsigned p067 = f2bfu(t0[6]) | (f2bfu(t0[7]) << 16);
    unsigned p089 = f2bfu(t0[8]) | (f2bfu(t0[9]) << 16);
    unsigned p101 = f2bfu(t1[0]) | (f2bfu(t1[1]) << 16);
    unsigned p123 = f2bfu(t1[2]) | (f2bfu(t1[3]) << 16);
    unsigned p145 = f2bfu(t1[4]) | (f2bfu(t1[5]) << 16);
    unsigned p167 = f2bfu(t1[6]) | (f2bfu(t1[7]) << 16);
    unsigned p189 = f2bfu(t1[8]) | (f2bfu(t1[9]) << 16);
    bd0.x = half ? p089 : p001;  bd0.y = half ? 0u : p023;
    bd0.z = half ? 0u : p045;    bd0.w = half ? 0u : p067;
    bd1.x = half ? p189 : p101;  bd1.y = half ? 0u : p123;
    bd1.z = half ? 0u : p145;    bd1.w = half ? 0u : p167;
    bf0 = __builtin_bit_cast(short8, bd0);
    bf1 = __builtin_bit_cast(short8, bd1);
  }

  // prefetch iteration 0
  int vu = __builtin_amdgcn_readfirstlane(waveG);
  int4   rec_n = meanws[vu];
  float4 pt_n  = ((const float4*)vf)[vu * P_ + p];

  #pragma unroll
  for (int it = 0; it < K3_ITERS; ++it) {
    const int4   rec = rec_n;
    const float4 pt  = pt_n;
    const int vcur = vu;
    if (it + 1 < K3_ITERS) {
      vu = __builtin_amdgcn_readfirstlane(waveG + (it + 1) * K3_WAVES);
      rec_n = meanws[vu];
      pt_n  = ((const float4*)vf)[vu * P_ + p];
    }

    const int cnt = rec.w;
    const bool pm = p < cnt;
    unsigned dx = f2bfu(pm ? pt.x : 0.f) | (f2bfu(pm ? pt.y : 0.f) << 16);
    unsigned dy = f2bfu(pm ? pt.z : 0.f) | (f2bfu(pm ? pt.w : 0.f) << 16);
    unsigned m01 = pm ? (unsigned)rec.x : 0u;
    unsigned m23 = pm ? (unsigned)rec.y : 0u;
    unsigned m45 = pm ? (unsigned)rec.z : 0u;
    uint4 adw;
    adw.x = half ? m45 : dx;
    adw.y = half ? 0u  : dy;
    adw.z = half ? 0u  : m01;
    adw.w = half ? 0u  : m23;
    short8 af = __builtin_bit_cast(short8, adw);

    floatx16 c0 = {}, c1 = {};
    c0 = __builtin_amdgcn_mfma_f32_32x32x16_bf16(af, bf0, c0, 0, 0, 0);
    c1 = __builtin_amdgcn_mfma_f32_32x32x16_bf16(af, bf1, c1, 0, 0, 0);

    float m0 = c0[0], m1 = c1[0];
    #pragma unroll
    for (int i = 1; i < 16; ++i) {
      m0 = fmaxf(m0, c0[i]);
      m1 = fmaxf(m1, c1[i]);
    }
    m0 = fmaxf(m0, __shfl_xor(m0, 32, 64));
    m1 = fmaxf(m1, __shfl_xor(m1, 32, 64));
    float y = half ? fmaxf(b1 + m1, 0.f) : fmaxf(b0 + m0, 0.f);
    out[vcur * COUT + lane] = y;
  }
}

extern "C" void kernel_launch(void* const* d_in, const int* in_sizes, int n_in,
                              void* d_out, int out_size, void* d_ws, size_t ws_size,
                              hipStream_t stream)
{
  const float* vf     = (const float*)d_in[0];
  const int*   npts   = (const int*)d_in[1];
  const int*   coords = (const int*)d_in[2];
  const float* Wm     = (const float*)d_in[3];
  const float* gamma  = (const float*)d_in[4];
  const float* beta   = (const float*)d_in[5];
  float* out = (float*)d_out;

  float* ws = (float*)d_ws;
  float* partials = ws;                               // 2500*72 floats
  float* ab       = ws + K1_BLOCKS * PSTRIDE;         // 128 floats
  int4*  meanws   = (int4*)(ws + K1_BLOCKS * PSTRIDE + 128);  // V_ int4

  k1_stats<<<K1_BLOCKS, 256, 0, stream>>>(vf, npts, coords, partials, meanws);
  k2_finalize<<<1, 704, 0, stream>>>(partials, Wm, gamma, beta, ab);
  k3_mfma<<<K3_BLOCKS, 256, 0, stream>>>(vf, Wm, ab, meanws, out);
}

// Round 6
// 140.533 us; speedup vs baseline: 1.2286x; 1.2286x over previous
//
#include <hip/hip_runtime.h>

// PillarVFE fused.
// k1: lane=voxel. Per-thread masked point moments P2(10)/T(4)/S(3) over 32 pts,
//     algebraic epilogue -> 65 f-moments, block reduce -> partials[391].
//     Also writes per-voxel packed record (-mean,-center bf16, cnt), coalesced.
// k2: single block reduces 391 rows (L1-resident) -> per-channel a,b.
// k3: A=[xyzw,-mean,-ctr]*mask in MFMA K-slots, B=a*W'' bf16, C=0 -> D=a*x;
//     out = relu(b + max_rows D). One wave = one voxel/iter, prefetched.

typedef __attribute__((ext_vector_type(8))) short short8;     // 8 bf16
typedef __attribute__((ext_vector_type(16))) float floatx16;  // 32x32 MFMA C/D

namespace {
constexpr int V_    = 100000;
constexpr int P_    = 32;
constexpr int COUT  = 64;
constexpr int NF    = 10;
constexpr int NMOM  = 65;
constexpr int PSTRIDE = 72;
constexpr int K1_BLOCKS = 391;    // ceil(100000/256) voxels, 1/thread
constexpr int K3_BLOCKS = 3125;   // 12500 waves x 8 iters = 100000 exactly
constexpr int K3_WAVES  = 12500;
constexpr int K3_ITERS  = 8;

constexpr float VX_ = 0.16f, VY_ = 0.16f, VZ_ = 4.0f;
constexpr float XOFF_ = 0.08f, YOFF_ = -39.60f, ZOFF_ = -1.0f;
constexpr float EPS_ = 0.001f;
}

__device__ __forceinline__ unsigned f2bfu(float x) {  // RNE -> 16-bit value
  unsigned u = __builtin_bit_cast(unsigned, x);
  u += 0x7fffu + ((u >> 16) & 1u);
  return u >> 16;
}

// ---------------- Pass 1 ----------------
__global__ __launch_bounds__(256) void k1_stats(
    const float* __restrict__ vf, const int* __restrict__ npts,
    const int* __restrict__ coords, float* __restrict__ partials,
    int4* __restrict__ meanws)
{
  const int tid = threadIdx.x;
  const int v   = blockIdx.x * 256 + tid;
  const bool valid = v < V_;

  float mom[NMOM];
  #pragma unroll
  for (int i = 0; i < NMOM; ++i) mom[i] = 0.f;

  if (valid) {
    const int  cnt = npts[v];
    const int4 cd  = ((const int4*)coords)[v];
    const float4* base = (const float4*)vf + (size_t)v * P_;

    float p2[10];
    #pragma unroll
    for (int i = 0; i < 10; ++i) p2[i] = 0.f;
    float tx = 0.f, ty = 0.f, tz = 0.f, tw = 0.f;
    float sx = 0.f, sy = 0.f, sz = 0.f;

    float4 buf[8];
    #pragma unroll
    for (int i = 0; i < 8; ++i) buf[i] = base[i];

    #pragma unroll
    for (int c = 0; c < 4; ++c) {
      float4 nxt[8];
      if (c < 3) {
        #pragma unroll
        for (int i = 0; i < 8; ++i) nxt[i] = base[(c + 1) * 8 + i];
      }
      #pragma unroll
      for (int i = 0; i < 8; ++i) {
        const int p = c * 8 + i;
        const float4 q = buf[i];
        const float msk = (p < cnt) ? 1.f : 0.f;
        sx += q.x; sy += q.y; sz += q.z;
        const float ux = q.x * msk, uy = q.y * msk;
        const float uz = q.z * msk, uw = q.w * msk;
        tx += ux; ty += uy; tz += uz; tw += uw;
        p2[0] += ux * ux; p2[1] += ux * uy; p2[2] += ux * uz; p2[3] += ux * uw;
        p2[4] += uy * uy; p2[5] += uy * uz; p2[6] += uy * uw;
        p2[7] += uz * uz; p2[8] += uz * uw;
        p2[9] += uw * uw;
      }
      if (c < 3) {
        #pragma unroll
        for (int i = 0; i < 8; ++i) buf[i] = nxt[i];
      }
    }

    const float cf = (float)cnt;
    const float rinv = 1.f / cf;
    const float gx = sx * rinv, gy = sy * rinv, gz = sz * rinv;
    const float hx = (float)cd.w * VX_ + XOFF_;
    const float hy = (float)cd.z * VY_ + YOFF_;
    const float hz = (float)cd.y * VZ_ + ZOFF_;

    // packed record for k3 (coalesced int4 store)
    {
      unsigned nm01 = f2bfu(-gx) | (f2bfu(-gy) << 16);
      unsigned nm23 = f2bfu(-gz) | (f2bfu(-hx) << 16);
      unsigned nm45 = f2bfu(-hy) | (f2bfu(-hz) << 16);
      meanws[v] = make_int4((int)nm01, (int)nm23, (int)nm45, cnt);
    }

    // f-moment reconstruction:
    // f_i = u[SIG[i]] - m*K[i];  M1_i = T[SIG[i]] - cnt*K[i]
    // M2_ij = P2[SIG i,SIG j] - K_i*T[SIG j] - K_j*T[SIG i] + cnt*K_i*K_j
    const int SIG[10] = {0,1,2,3, 0,1,2, 0,1,2};
    const float K[10] = {0.f,0.f,0.f,0.f, gx,gy,gz, hx,hy,hz};
    const float Tm[4] = {tx,ty,tz,tw};
    const int I44[4][4] = {{0,1,2,3},{1,4,5,6},{2,5,7,8},{3,6,8,9}};

    #pragma unroll
    for (int i = 0; i < 10; ++i) mom[i] = Tm[SIG[i]] - cf * K[i];
    int idx = NF;
    #pragma unroll
    for (int i = 0; i < 10; ++i)
      #pragma unroll
      for (int j = i; j < 10; ++j) {
        mom[idx++] = p2[I44[SIG[i]][SIG[j]]]
                   - K[i] * Tm[SIG[j]] - K[j] * Tm[SIG[i]]
                   + cf * K[i] * K[j];
      }
  }

  // one-time 64-lane butterfly per moment
  #pragma unroll
  for (int i = 0; i < NMOM; ++i) {
    float a = mom[i];
    #pragma unroll
    for (int m = 32; m >= 1; m >>= 1) a += __shfl_xor(a, m, 64);
    mom[i] = a;
  }

  __shared__ float red[4][NMOM];
  if ((tid & 63) == 0) {
    int w = tid >> 6;
    #pragma unroll
    for (int i = 0; i < NMOM; ++i) red[w][i] = mom[i];
  }
  __syncthreads();
  if (tid < NMOM) {
    partials[blockIdx.x * PSTRIDE + tid] =
        (red[0][tid] + red[1][tid]) + (red[2][tid] + red[3][tid]);
  }
}

// ---------------- Pass 2 ----------------
__global__ __launch_bounds__(704) void k2_finalize(
    const float* __restrict__ partials, const float* __restrict__ Wm,
    const float* __restrict__ gamma, const float* __restrict__ beta,
    float* __restrict__ ab)
{
  __shared__ float s1[10 * NMOM];
  __shared__ double S[NMOM];
  const int t = threadIdx.x;

  if (t < 10 * NMOM) {   // 650 threads, 10 chunks x 40 rows (391 total)
    const int col = t % NMOM, chunk = t / NMOM;
    const int base = chunk * 40;
    float a0 = 0.f, a1 = 0.f, a2 = 0.f, a3 = 0.f;
    #pragma unroll 4
    for (int i = 0; i < 40; i += 4) {
      int r0 = base + i;
      if (r0 + 0 < K1_BLOCKS) a0 += partials[(r0 + 0) * PSTRIDE + col];
      if (r0 + 1 < K1_BLOCKS) a1 += partials[(r0 + 1) * PSTRIDE + col];
      if (r0 + 2 < K1_BLOCKS) a2 += partials[(r0 + 2) * PSTRIDE + col];
      if (r0 + 3 < K1_BLOCKS) a3 += partials[(r0 + 3) * PSTRIDE + col];
    }
    s1[chunk * NMOM + col] = (a0 + a1) + (a2 + a3);
  }
  __syncthreads();
  if (t < NMOM) {
    double d = 0.0;
    #pragma unroll
    for (int c = 0; c < 10; ++c) d += (double)s1[c * NMOM + t];
    S[t] = d;
  }
  __syncthreads();
  if (t < COUT) {
    const double N = (double)V_ * (double)P_;
    double w[NF];
    #pragma unroll
    for (int c = 0; c < NF; ++c) w[c] = (double)Wm[t * NF + c];
    double mean = 0.0;
    #pragma unroll
    for (int c = 0; c < NF; ++c) mean += w[c] * S[c];
    mean /= N;
    double ex2 = 0.0;
    int idx = NF;
    #pragma unroll
    for (int c = 0; c < NF; ++c)
      #pragma unroll
      for (int c2 = c; c2 < NF; ++c2) {
        double coef = (c == c2) ? 1.0 : 2.0;
        ex2 += coef * w[c] * w[c2] * S[idx++];
      }
    ex2 /= N;
    double var = ex2 - mean * mean;
    double rs = 1.0 / sqrt(var + (double)EPS_);
    double a = (double)gamma[t] * rs;
    double b = (double)beta[t] - mean * a;
    ab[t] = (float)a;
    ab[COUT + t] = (float)b;
  }
}

// ---------------- Pass 3 ----------------
__global__ __launch_bounds__(256) void k3_mfma(
    const float* __restrict__ vf, const float* __restrict__ Wm,
    const float* __restrict__ ab, const int4* __restrict__ meanws,
    float* __restrict__ out)
{
  const int tid  = threadIdx.x;
  const int lane = tid & 63;
  const int p    = lane & 31;
  const int half = lane >> 5;
  const int waveG = blockIdx.x * 4 + (tid >> 6);   // 0..12499

  // B fragments: B[k][n], n = lane&31, k = half*8+j.
  // k0..3: a*(W0+W4+W7, W1+W5+W8, W2+W6+W9, W3); k4..9: a*(W4..W9).
  const float a0 = ab[p],      b0 = ab[COUT + p];
  const float a1 = ab[32 + p], b1 = ab[COUT + 32 + p];
  short8 bf0, bf1;
  {
    const float* w0 = &Wm[p * NF];
    const float* w1 = &Wm[(32 + p) * NF];
    float t0[NF], t1[NF];
    t0[0] = a0 * (w0[0] + w0[4] + w0[7]);
    t0[1] = a0 * (w0[1] + w0[5] + w0[8]);
    t0[2] = a0 * (w0[2] + w0[6] + w0[9]);
    t0[3] = a0 * w0[3];
    t1[0] = a1 * (w1[0] + w1[4] + w1[7]);
    t1[1] = a1 * (w1[1] + w1[5] + w1[8]);
    t1[2] = a1 * (w1[2] + w1[6] + w1[9]);
    t1[3] = a1 * w1[3];
    #pragma unroll
    for (int k = 4; k < NF; ++k) { t0[k] = a0 * w0[k]; t1[k] = a1 * w1[k]; }

    uint4 bd0, bd1;
    unsigned p001 = f2bfu(t0[0]) | (f2bfu(t0[1]) << 16);
    unsigned p023 = f2bfu(t0[2]) | (f2bfu(t0[3]) << 16);
    unsigned p045 = f2bfu(t0[4]) | (f2bfu(t0[5]) << 16);
    unsigned p067 = f2bfu(t0[6]) | (f2bfu(t0[7]) << 16);
    unsigned p089 = f2bfu(t0[8]) | (f2bfu(t0[9]) << 16);
    unsigned p101 = f2bfu(t1[0]) | (f2bfu(t1[1]) << 16);
    unsigned p123 = f2bfu(t1[2]) | (f2bfu(t1[3]) << 16);
    unsigned p145 = f2bfu(t1[4]) | (f2bfu(t1[5]) << 16);
    unsigned p167 = f2bfu(t1[6]) | (f2bfu(t1[7]) << 16);
    unsigned p189 = f2bfu(t1[8]) | (f2bfu(t1[9]) << 16);
    bd0.x = half ? p089 : p001;  bd0.y = half ? 0u : p023;
    bd0.z = half ? 0u : p045;    bd0.w = half ? 0u : p067;
    bd1.x = half ? p189 : p101;  bd1.y = half ? 0u : p123;
    bd1.z = half ? 0u : p145;    bd1.w = half ? 0u : p167;
    bf0 = __builtin_bit_cast(short8, bd0);
    bf1 = __builtin_bit_cast(short8, bd1);
  }

  // prefetch iteration 0
  int vu = __builtin_amdgcn_readfirstlane(waveG);
  int4   rec_n = meanws[vu];
  float4 pt_n  = ((const float4*)vf)[vu * P_ + p];

  #pragma unroll
  for (int it = 0; it < K3_ITERS; ++it) {
    const int4   rec = rec_n;
    const float4 pt  = pt_n;
    const int vcur = vu;
    if (it + 1 < K3_ITERS) {
      vu = __builtin_amdgcn_readfirstlane(waveG + (it + 1) * K3_WAVES);
      rec_n = meanws[vu];
      pt_n  = ((const float4*)vf)[vu * P_ + p];
    }

    const int cnt = rec.w;
    const bool pm = p < cnt;
    unsigned dx = f2bfu(pm ? pt.x : 0.f) | (f2bfu(pm ? pt.y : 0.f) << 16);
    unsigned dy = f2bfu(pm ? pt.z : 0.f) | (f2bfu(pm ? pt.w : 0.f) << 16);
    unsigned m01 = pm ? (unsigned)rec.x : 0u;
    unsigned m23 = pm ? (unsigned)rec.y : 0u;
    unsigned m45 = pm ? (unsigned)rec.z : 0u;
    uint4 adw;
    adw.x = half ? m45 : dx;
    adw.y = half ? 0u  : dy;
    adw.z = half ? 0u  : m01;
    adw.w = half ? 0u  : m23;
    short8 af = __builtin_bit_cast(short8, adw);

    floatx16 c0 = {}, c1 = {};
    c0 = __builtin_amdgcn_mfma_f32_32x32x16_bf16(af, bf0, c0, 0, 0, 0);
    c1 = __builtin_amdgcn_mfma_f32_32x32x16_bf16(af, bf1, c1, 0, 0, 0);

    float m0 = c0[0], m1 = c1[0];
    #pragma unroll
    for (int i = 1; i < 16; ++i) {
      m0 = fmaxf(m0, c0[i]);
      m1 = fmaxf(m1, c1[i]);
    }
    m0 = fmaxf(m0, __shfl_xor(m0, 32, 64));
    m1 = fmaxf(m1, __shfl_xor(m1, 32, 64));
    float y = half ? fmaxf(b1 + m1, 0.f) : fmaxf(b0 + m0, 0.f);
    out[vcur * COUT + lane] = y;
  }
}

extern "C" void kernel_launch(void* const* d_in, const int* in_sizes, int n_in,
                              void* d_out, int out_size, void* d_ws, size_t ws_size,
                              hipStream_t stream)
{
  const float* vf     = (const float*)d_in[0];
  const int*   npts   = (const int*)d_in[1];
  const int*   coords = (const int*)d_in[2];
  const float* Wm     = (const float*)d_in[3];
  const float* gamma  = (const float*)d_in[4];
  const float* beta   = (const float*)d_in[5];
  float* out = (float*)d_out;

  float* ws = (float*)d_ws;
  float* partials = ws;                               // 391*72 floats
  float* ab       = ws + K1_BLOCKS * PSTRIDE;         // 128 floats
  int4*  meanws   = (int4*)(ws + K1_BLOCKS * PSTRIDE + 128);  // V_ int4 (16B-aligned)

  k1_stats<<<K1_BLOCKS, 256, 0, stream>>>(vf, npts, coords, partials, meanws);
  k2_finalize<<<1, 704, 0, stream>>>(partials, Wm, gamma, beta, ab);
  k3_mfma<<<K3_BLOCKS, 256, 0, stream>>>(vf, Wm, ab, meanws, out);
}